// Round 6
// baseline (2469.720 us; speedup 1.0000x reference)
//
#include <hip/hip_runtime.h>
#include <hip/hip_bf16.h>

typedef __bf16 bf16;
typedef __bf16 bf16x8 __attribute__((ext_vector_type(8)));
typedef float f32x4 __attribute__((ext_vector_type(4)));
typedef float f32x16 __attribute__((ext_vector_type(16)));

#define S_ 512
#define N_ 64
#define C_ 512
#define V_ 10
#define Q_ 256

// ---- workspace layout (bytes) ----
#define OFF_A0   ((size_t)0)
#define OFF_A1   (OFF_A0 + (size_t)S_ * N_ * 4)
#define OFF_PW   (OFF_A1 + (size_t)S_ * N_ * 4)            // bf16 [N][Q][S]
#define OFF_QU   (OFF_PW + (size_t)N_ * Q_ * S_ * 2)       // bf16 [Q][N][C]
#define OFF_HP   (OFF_QU + (size_t)Q_ * N_ * C_ * 2)       // u32 [2][N][C] tagged h
#define OFF_HS   (OFF_HP + (size_t)2 * N_ * C_ * 4)        // bf16 [Q][N][C]
#define OFF_CTRL (OFF_HS + (size_t)Q_ * N_ * C_ * 2)       // int summary[64]

__device__ __forceinline__ float sigf(float x) { return 1.f / (1.f + __expf(-x)); }
__device__ __forceinline__ float tanhf_(float x) { return 1.f - 2.f / (__expf(2.f * x) + 1.f); }

// ---------------- stage 1: action softmax ----------------
__global__ __launch_bounds__(256) void k_actions(const float* __restrict__ mem,
    const float* __restrict__ Wact, const float* __restrict__ bact,
    float* __restrict__ A0, float* __restrict__ A1) {
  const int wid = threadIdx.x >> 6, lane = threadIdx.x & 63;
  const int row = blockIdx.x * 4 + wid;          // row = s*64 + n
  const int s = row >> 6, n = row & 63;
  const float* mrow = mem + (size_t)row * C_ + lane * 8;
  const float* wrow = Wact + (size_t)lane * 16;
  float4 m0 = *(const float4*)(mrow);
  float4 m1 = *(const float4*)(mrow + 4);
  float d0 = 0.f, d1 = 0.f;
  float mv[8] = {m0.x, m0.y, m0.z, m0.w, m1.x, m1.y, m1.z, m1.w};
#pragma unroll
  for (int j = 0; j < 8; ++j) {
    d0 += mv[j] * wrow[j * 2 + 0];
    d1 += mv[j] * wrow[j * 2 + 1];
  }
#pragma unroll
  for (int m = 32; m >= 1; m >>= 1) {
    d0 += __shfl_xor(d0, m);
    d1 += __shfl_xor(d1, m);
  }
  if (lane == 0) {
    float l0 = d0 + bact[0], l1 = d1 + bact[1];
    float mx = fmaxf(l0, l1);
    float e0 = __expf(l0 - mx), e1 = __expf(l1 - mx);
    float inv = 1.f / (e0 + e1);
    A0[(size_t)n * S_ + s] = e0 * inv;
    A1[(size_t)n * S_ + s] = e1 * inv;
  }
}

// ---------------- stage 2: posvec scan ----------------
__global__ __launch_bounds__(256) void k_posvec(const float* __restrict__ A0,
    const float* __restrict__ A1, bf16* __restrict__ Pw) {
  __shared__ float a0s[S_], a1s[S_];
  __shared__ float pbuf[2][Q_];
  const int n = blockIdx.x, t = threadIdx.x;
  a0s[t] = A0[(size_t)n * S_ + t];
  a0s[t + 256] = A0[(size_t)n * S_ + t + 256];
  a1s[t] = A1[(size_t)n * S_ + t];
  a1s[t + 256] = A1[(size_t)n * S_ + t + 256];
  float p = (t == 0) ? 1.f : 0.f;
  __syncthreads();
  for (int s8 = 0; s8 < S_; s8 += 8) {
    float emit[8];
#pragma unroll
    for (int jj = 0; jj < 8; ++jj) {
      const int s = s8 + jj;
      pbuf[jj & 1][t] = p;
      __syncthreads();
      float pm1 = pbuf[jj & 1][(t + Q_ - 1) & (Q_ - 1)];
      float a0 = a0s[s], a1 = a1s[s];
      emit[jj] = p * a1;
      p = fmaf(pm1, a1, p * a0);
    }
    bf16x8 v;
#pragma unroll
    for (int jj = 0; jj < 8; ++jj) v[jj] = (bf16)emit[jj];
    *(bf16x8*)(Pw + ((size_t)n * Q_ + t) * S_ + s8) = v;
  }
}

// ---------------- stage 3: queue einsum ----------------
__global__ __launch_bounds__(256) void k_queue(const bf16* __restrict__ Pw,
    const float* __restrict__ mem, bf16* __restrict__ qout) {
  __shared__ bf16 bt[64 * 32];
  const int bid = blockIdx.x;
  const int n = bid >> 5, qt = (bid >> 3) & 3, ct = bid & 7;
  const int q0 = qt * 64, c0 = ct * 64;
  const int t = threadIdx.x, wid = t >> 6, lane = t & 63;
  const int lrow = lane & 15, lkb = lane >> 4;
  f32x4 acc[4] = {};
  const bf16* arow = Pw + ((size_t)n * Q_ + q0 + wid * 16 + lrow) * S_ + lkb * 8;
  const int sl = t >> 3, cb = (t & 7) * 8;
  const float* msrc = mem + ((size_t)sl * N_ + n) * C_ + c0 + cb;
  for (int kb = 0; kb < 16; ++kb) {
    float4 f0 = *(const float4*)(msrc + (size_t)kb * 32 * N_ * C_);
    float4 f1 = *(const float4*)(msrc + (size_t)kb * 32 * N_ * C_ + 4);
    __syncthreads();
    float fv[8] = {f0.x, f0.y, f0.z, f0.w, f1.x, f1.y, f1.z, f1.w};
#pragma unroll
    for (int jw = 0; jw < 8; ++jw) {
      const int row = cb + jw;
      bt[row * 32 + ((((sl >> 3) ^ (row & 3)) << 3) | (sl & 7))] = (bf16)fv[jw];
    }
    __syncthreads();
    bf16x8 a = *(const bf16x8*)(arow + kb * 32);
#pragma unroll
    for (int cs = 0; cs < 4; ++cs) {
      const int row = cs * 16 + lrow;
      bf16x8 b = *(const bf16x8*)(&bt[row * 32 + ((lkb ^ (row & 3)) << 3)]);
      acc[cs] = __builtin_amdgcn_mfma_f32_16x16x32_bf16(a, b, acc[cs], 0, 0, 0);
    }
  }
#pragma unroll
  for (int cs = 0; cs < 4; ++cs) {
#pragma unroll
    for (int r = 0; r < 4; ++r) {
      const int q = q0 + wid * 16 + (lane >> 4) * 4 + r;
      const int c = c0 + cs * 16 + lrow;
      qout[((size_t)q * N_ + n) * C_ + c] = (bf16)acc[cs][r];
    }
  }
}

// ---------------- stage 4: LSTM — sentinel-tagged h, no flags, no drains ----------------
// Hp word = (tag<<16)|bf16(h); tag = step at which this h is consumed.
// Writers fire-and-forget; readers self-verify tags, chunked 2-deep pipeline.
// Advisory summary[64] (zeroed ctrl) gates the pipeline to make re-polls rare.

#define ISSUE_CHUNK(BUF, C8)                                                    \
  {                                                                             \
    _Pragma("unroll") for (int i_ = 0; i_ < 8; ++i_)                            \
        asm volatile("global_load_dwordx4 %0, %1, off offset:%2 sc0 sc1"        \
                     : "=v"(BUF[i_])                                            \
                     : "v"(hb), "i"(((C8) * 4 + (i_ >> 1)) * 64 + (i_ & 1) * 16)); \
  }

#define CHECK_CHUNK(BUF, OKV)                                                   \
  {                                                                             \
    unsigned a_ = 0;                                                            \
    _Pragma("unroll") for (int i_ = 0; i_ < 8; ++i_) {                          \
      a_ |= (BUF[i_].x ^ want); a_ |= (BUF[i_].y ^ want);                       \
      a_ |= (BUF[i_].z ^ want); a_ |= (BUF[i_].w ^ want);                       \
    }                                                                           \
    OKV = (a_ < 0x10000u);                                                      \
  }

#define CONSUME_CHUNK(BUF, C8)                                                  \
  {                                                                             \
    _Pragma("unroll") for (int k_ = 0; k_ < 4; ++k_) {                          \
      union { unsigned u[4]; bf16x8 v; } cv_;                                   \
      cv_.u[0] = (BUF[k_ * 2].y << 16) | (BUF[k_ * 2].x & 0xffffu);             \
      cv_.u[1] = (BUF[k_ * 2].w << 16) | (BUF[k_ * 2].z & 0xffffu);             \
      cv_.u[2] = (BUF[k_ * 2 + 1].y << 16) | (BUF[k_ * 2 + 1].x & 0xffffu);     \
      cv_.u[3] = (BUF[k_ * 2 + 1].w << 16) | (BUF[k_ * 2 + 1].z & 0xffffu);     \
      const int kb_ = (C8) * 4 + k_;                                            \
      acc[kb_ & 1] = __builtin_amdgcn_mfma_f32_32x32x16_bf16(cv_.v, bw[kb_],    \
                                                             acc[kb_ & 1], 0, 0, 0); \
    }                                                                           \
  }

#define CHUNK_STEP(C8, X, Y)                                                    \
  {                                                                             \
    if ((C8) < 7) {                                                             \
      ISSUE_CHUNK(Y, (C8) + 1);                                                 \
      asm volatile("s_waitcnt vmcnt(8)" ::: "memory");                          \
    } else {                                                                    \
      asm volatile("s_waitcnt vmcnt(0)" ::: "memory");                          \
    }                                                                           \
    __builtin_amdgcn_sched_barrier(0);                                          \
    int ok_;                                                                    \
    CHECK_CHUNK(X, ok_);                                                        \
    while (!__all(ok_)) {                                                       \
      ISSUE_CHUNK(X, C8);                                                       \
      asm volatile("s_waitcnt vmcnt(0)" ::: "memory");                          \
      __builtin_amdgcn_sched_barrier(0);                                        \
      CHECK_CHUNK(X, ok_);                                                      \
    }                                                                           \
    CONSUME_CHUNK(X, C8)                                                        \
  }

__global__ __launch_bounds__(256, 1) void k_lstm(
    const bf16* __restrict__ queue, const float* __restrict__ Wih,
    const float* __restrict__ Whh, const float* __restrict__ bih,
    const float* __restrict__ bhh, unsigned* __restrict__ Hp,
    bf16* __restrict__ hs, int* __restrict__ summ) {
  __shared__ float gx[2][2][32][33];  // [step parity][Mblk][row][col]
  __shared__ float gh[2][32][33];     // [Mblk][row][col]
  __shared__ float bias[32];
  const int w = blockIdx.x, t = threadIdx.x;
  const int wid = t >> 6, lane = t & 63;
  const int mat = wid >> 1;   // 0 = x (W_ih), 1 = h (W_hh)
  const int blk = wid & 1;    // n-rows blk*32 .. +32

  // weight B-fragments -> registers
  const int col = lane & 31;                 // gate col j: gate=j&3, ch=w*8+(j>>2)
  const int kg = (lane >> 5) * 8;
  const int wr = (col & 3) * 512 + w * 8 + (col >> 2);
  const float* Wsrc = (mat ? Whh : Wih) + (size_t)wr * C_ + kg;
  bf16x8 bw[32];
#pragma unroll
  for (int kb = 0; kb < 32; ++kb) {
    float4 wa = *(const float4*)(Wsrc + kb * 16);
    float4 wb = *(const float4*)(Wsrc + kb * 16 + 4);
    bf16x8 v;
    v[0] = (bf16)wa.x; v[1] = (bf16)wa.y; v[2] = (bf16)wa.z; v[3] = (bf16)wa.w;
    v[4] = (bf16)wb.x; v[5] = (bf16)wb.y; v[6] = (bf16)wb.z; v[7] = (bf16)wb.w;
    bw[kb] = v;
  }
  if (t < 32) {
    const int rr = (t & 3) * 512 + w * 8 + (t >> 2);
    bias[t] = bih[rr] + bhh[rr];
  }

  const int en = t >> 2, ep = t & 3;         // elementwise: n=en, channels w*8+2ep,+1
  {  // init own slice: buf0 = h(0)=0 tag 0; buf1 = poison tag 0xFFFF (replay safety)
    uint2 z0; z0.x = 0u; z0.y = 0u;
    uint2 z1; z1.x = 0xFFFF0000u; z1.y = 0xFFFF0000u;
    unsigned* p0 = Hp + ((size_t)0 * N_ + en) * C_ + w * 8 + ep * 2;
    unsigned* p1 = Hp + ((size_t)1 * N_ + en) * C_ + w * 8 + ep * 2;
    asm volatile("global_store_dwordx2 %0, %1, off sc0 sc1" :: "v"(p0), "v"(z0) : "memory");
    asm volatile("global_store_dwordx2 %0, %1, off sc0 sc1" :: "v"(p1), "v"(z1) : "memory");
    asm volatile("s_waitcnt vmcnt(0)" ::: "memory");  // order init vs later same-addr writes
  }

  float cs0 = 0.f, cs1 = 0.f;
  const int eb = en >> 5, er = en & 31, j0 = ep * 8;

  bf16x8 xf[32];  // x A-fragments (holds x(step+1) at loop top)
  if (mat == 0) {
    const bf16* xb = queue + ((size_t)0 * N_ + blk * 32 + (lane & 31)) * C_ + kg;
#pragma unroll
    for (int kb = 0; kb < 32; ++kb) xf[kb] = *(const bf16x8*)(xb + kb * 16);
    {  // gx for step 0
      f32x16 acc[2] = {};
#pragma unroll
      for (int kb = 0; kb < 32; ++kb)
        acc[kb & 1] = __builtin_amdgcn_mfma_f32_32x32x16_bf16(xf[kb], bw[kb], acc[kb & 1], 0, 0, 0);
      f32x16 asum = acc[0] + acc[1];
#pragma unroll
      for (int rg = 0; rg < 16; ++rg) {
        const int rl = (rg & 3) + 8 * (rg >> 2) + 4 * (lane >> 5);
        gx[0][blk][rl][col] = asum[rg];
      }
    }
    const bf16* xb1 = queue + ((size_t)1 * N_ + blk * 32 + (lane & 31)) * C_ + kg;
#pragma unroll
    for (int kb = 0; kb < 32; ++kb) xf[kb] = *(const bf16x8*)(xb1 + kb * 16);
  }

  for (int step = 0; step < Q_; ++step) {
    const int p = step & 1;
    const int cur = p, nxt = p ^ 1;
    if (mat == 1) {
      {  // advisory summary poll (capped; correctness via chunk tags)
        int v, it = 0;
        const int* fa = summ + lane;
        do {
          asm volatile("global_load_dword %0, %1, off sc0 sc1" : "=v"(v) : "v"(fa));
          asm volatile("s_waitcnt vmcnt(0)" ::: "memory");
        } while (__any(v < step) && ++it < 16384);
      }
      __builtin_amdgcn_sched_barrier(0);
      const unsigned want = (unsigned)step << 16;
      unsigned* hb = Hp + ((size_t)cur * N_ + blk * 32 + (lane & 31)) * C_ + kg;
      f32x16 acc[2] = {};
      uint4 ba[8], bb[8];
      ISSUE_CHUNK(ba, 0);
      CHUNK_STEP(0, ba, bb);
      CHUNK_STEP(1, bb, ba);
      CHUNK_STEP(2, ba, bb);
      CHUNK_STEP(3, bb, ba);
      CHUNK_STEP(4, ba, bb);
      CHUNK_STEP(5, bb, ba);
      CHUNK_STEP(6, ba, bb);
      CHUNK_STEP(7, bb, ba);
      f32x16 asum = acc[0] + acc[1];
#pragma unroll
      for (int rg = 0; rg < 16; ++rg) {
        const int rl = (rg & 3) + 8 * (rg >> 2) + 4 * (lane >> 5);
        gh[blk][rl][col] = asum[rg];
      }
    } else if (step + 1 < Q_) {
      // x-waves: gates for step+1 from prefetched xf
      f32x16 acc[2] = {};
#pragma unroll
      for (int kb = 0; kb < 32; ++kb)
        acc[kb & 1] = __builtin_amdgcn_mfma_f32_32x32x16_bf16(xf[kb], bw[kb], acc[kb & 1], 0, 0, 0);
      f32x16 asum = acc[0] + acc[1];
#pragma unroll
      for (int rg = 0; rg < 16; ++rg) {
        const int rl = (rg & 3) + 8 * (rg >> 2) + 4 * (lane >> 5);
        gx[p ^ 1][blk][rl][col] = asum[rg];
      }
    }
    __syncthreads();  // S1: gh + gx[p] ready

    {  // elementwise: n=en, channels w*8+2ep,+1; c-state in registers
      float g0 = gx[p][eb][er][j0 + 0] + gh[eb][er][j0 + 0] + bias[j0 + 0];
      float g1 = gx[p][eb][er][j0 + 1] + gh[eb][er][j0 + 1] + bias[j0 + 1];
      float g2 = gx[p][eb][er][j0 + 2] + gh[eb][er][j0 + 2] + bias[j0 + 2];
      float g3 = gx[p][eb][er][j0 + 3] + gh[eb][er][j0 + 3] + bias[j0 + 3];
      cs0 = sigf(g1) * cs0 + sigf(g0) * tanhf_(g2);
      float h0v = sigf(g3) * tanhf_(cs0);
      float g4 = gx[p][eb][er][j0 + 4] + gh[eb][er][j0 + 4] + bias[j0 + 4];
      float g5 = gx[p][eb][er][j0 + 5] + gh[eb][er][j0 + 5] + bias[j0 + 5];
      float g6 = gx[p][eb][er][j0 + 6] + gh[eb][er][j0 + 6] + bias[j0 + 6];
      float g7 = gx[p][eb][er][j0 + 7] + gh[eb][er][j0 + 7] + bias[j0 + 7];
      cs1 = sigf(g5) * cs1 + sigf(g4) * tanhf_(g6);
      float h1v = sigf(g7) * tanhf_(cs1);
      unsigned lo = (unsigned)__builtin_bit_cast(unsigned short, (bf16)h0v);
      unsigned hi = (unsigned)__builtin_bit_cast(unsigned short, (bf16)h1v);
      const unsigned tagv = (unsigned)(step + 1) << 16;
      uint2 pr; pr.x = tagv | lo; pr.y = tagv | hi;
      unsigned* Hq = Hp + ((size_t)nxt * N_ + en) * C_ + w * 8 + ep * 2;
      asm volatile("global_store_dwordx2 %0, %1, off sc0 sc1" :: "v"(Hq), "v"(pr) : "memory");
      *((unsigned*)hs + ((size_t)step * N_ + en) * (C_ / 2) + w * 4 + ep) = (hi << 16) | lo;
    }
    if (mat == 0 && step + 2 < Q_) {  // prefetch x(step+2)
      const bf16* xb = queue + ((size_t)(step + 2) * N_ + blk * 32 + (lane & 31)) * C_ + kg;
#pragma unroll
      for (int kb = 0; kb < 32; ++kb) xf[kb] = *(const bf16x8*)(xb + kb * 16);
    }
    __syncthreads();  // S2: fences gx parity reuse; all h stores issued
    if (t == 0 && step + 1 < Q_) {  // advisory summary update (fire-and-forget)
      int sv = step + 1; int* sp = summ + w;
      asm volatile("global_store_dword %0, %1, off sc0 sc1" :: "v"(sp), "v"(sv) : "memory");
    }
  }
}

// ---------------- stage 5: LayerNorm + decode ----------------
__global__ __launch_bounds__(256) void k_lndec(const bf16* __restrict__ hs,
    const float* __restrict__ gamma, const float* __restrict__ beta,
    const float* __restrict__ Wdec, const float* __restrict__ bdec,
    float* __restrict__ out) {
  const int wid = threadIdx.x >> 6, lane = threadIdx.x & 63;
  const int row = blockIdx.x * 4 + wid;
  const bf16* hrow = hs + (size_t)row * C_ + lane * 8;
  bf16x8 hv = *(const bf16x8*)hrow;
  float h[8];
  float sm = 0.f, sq = 0.f;
#pragma unroll
  for (int j = 0; j < 8; ++j) {
    h[j] = (float)hv[j];
    sm += h[j];
    sq += h[j] * h[j];
  }
#pragma unroll
  for (int m = 32; m >= 1; m >>= 1) {
    sm += __shfl_xor(sm, m);
    sq += __shfl_xor(sq, m);
  }
  const float mu = sm * (1.f / C_);
  const float var = sq * (1.f / C_) - mu * mu;
  const float rs = 1.f / sqrtf(var + 1e-5f);
  float o[V_] = {};
#pragma unroll
  for (int j = 0; j < 8; ++j) {
    const int cj = lane * 8 + j;
    const float nv = (h[j] - mu) * rs * gamma[cj] + beta[cj];
    const float* wr = Wdec + (size_t)cj * V_;
#pragma unroll
    for (int v = 0; v < V_; ++v) o[v] += nv * wr[v];
  }
#pragma unroll
  for (int v = 0; v < V_; ++v) {
#pragma unroll
    for (int m = 32; m >= 1; m >>= 1) o[v] += __shfl_xor(o[v], m);
  }
  if (lane == 0) {
#pragma unroll
    for (int v = 0; v < V_; ++v) out[(size_t)row * V_ + v] = o[v] + bdec[v];
  }
}

extern "C" void kernel_launch(void* const* d_in, const int* in_sizes, int n_in,
                              void* d_out, int out_size, void* d_ws, size_t ws_size,
                              hipStream_t stream) {
  (void)in_sizes; (void)n_in; (void)out_size; (void)ws_size;
  const float* mem  = (const float*)d_in[0];
  const float* Wact = (const float*)d_in[1];
  const float* bact = (const float*)d_in[2];
  const float* Wih  = (const float*)d_in[3];
  const float* Whh  = (const float*)d_in[4];
  const float* bih  = (const float*)d_in[5];
  const float* bhh  = (const float*)d_in[6];
  const float* gam  = (const float*)d_in[7];
  const float* bet  = (const float*)d_in[8];
  const float* Wdec = (const float*)d_in[9];
  const float* bdec = (const float*)d_in[10];
  float* out = (float*)d_out;

  char* ws = (char*)d_ws;
  float* A0    = (float*)(ws + OFF_A0);
  float* A1    = (float*)(ws + OFF_A1);
  bf16* Pw     = (bf16*)(ws + OFF_PW);
  bf16* qu     = (bf16*)(ws + OFF_QU);
  unsigned* Hp = (unsigned*)(ws + OFF_HP);
  bf16* hs     = (bf16*)(ws + OFF_HS);
  int* ctrl    = (int*)(ws + OFF_CTRL);

  hipMemsetAsync(ctrl, 0, 4096, stream);
  k_actions<<<(S_ * N_) / 4, 256, 0, stream>>>(mem, Wact, bact, A0, A1);
  k_posvec<<<N_, 256, 0, stream>>>(A0, A1, Pw);
  k_queue<<<N_ * 32, 256, 0, stream>>>(Pw, mem, qu);
  k_lstm<<<64, 256, 0, stream>>>(qu, Wih, Whh, bih, bhh, Hp, hs, ctrl);
  k_lndec<<<(Q_ * N_) / 4, 256, 0, stream>>>(hs, gam, bet, Wdec, bdec, out);
}